// Round 6
// baseline (1560.088 us; speedup 1.0000x reference)
//
#include <hip/hip_runtime.h>

#define BN_   16
#define NPTS  4096
#define DFEAT 6
#define SCTR  1024
#define KNN   32
#define RTOT  (BN_*SCTR*KNN)   /* 524288 rows */
#define EPSV  1e-5f
#define RNF   524288.0f
#define NREP  64               /* replicated stats copies */

__device__ __forceinline__ float fmulx(float a, float b){ return __fmul_rn(a,b); }
__device__ __forceinline__ float faddx(float a, float b){ return __fadd_rn(a,b); }
__device__ __forceinline__ float fsubx(float a, float b){ return __fsub_rn(a,b); }
// naive (non-FMA) sum of squares — LOCKED by R5/R6 pass.
__device__ __forceinline__ float sq3x(float x, float y, float z){
  return faddx(faddx(fmulx(x,x), fmulx(y,y)), fmulx(z,z));
}
// FMA-contracted inner product (matches np einsum) — LOCKED by R5 pass.
__device__ __forceinline__ float dot3fma(float ax, float ay, float az,
                                         float bx, float by, float bz){
  return __fmaf_rn(az, bz, __fmaf_rn(ay, by, __fmul_rn(ax, bx)));
}

__device__ __forceinline__ unsigned fkey(float f){
  unsigned u = __float_as_uint(f);
  return (u & 0x80000000u) ? ~u : (u | 0x80000000u);
}
__device__ __forceinline__ float funkey(unsigned k){
  return (k & 0x80000000u) ? __uint_as_float(k & 0x7fffffffu) : __uint_as_float(~k);
}

// ---------------- DPP wave64 reductions (VALU-only; proven on HW in R12).
// R17 POST-MORTEM: DPP row-sum chains in wide-unrolled stats EPILOGUES spill
// (VGPR=256, 9.7 GB scratch HBM). DPP stays ONLY in argmax reductions.
// R19 POST-MORTEM: merged u64 (value,~j) DPP chain is NOT cheaper than two
// u32 chains (u64 cmp+2×cndmask per step ≈ both u32 chains' cost) — REGRESSED
// +37 µs with the pre-chain gather. k_fps is FROZEN at the R12/R14 form.
template<int CTRL>
__device__ __forceinline__ unsigned dpp_mv(unsigned v){
  return (unsigned)__builtin_amdgcn_update_dpp((int)v, (int)v, CTRL, 0xf, 0xf, false);
}
__device__ __forceinline__ unsigned wave_umax_b(unsigned v){
  unsigned o;
  o=dpp_mv<0x111>(v); v=v>o?v:o;   // row_shr:1
  o=dpp_mv<0x112>(v); v=v>o?v:o;   // row_shr:2
  o=dpp_mv<0x114>(v); v=v>o?v:o;   // row_shr:4
  o=dpp_mv<0x118>(v); v=v>o?v:o;   // row_shr:8
  o=dpp_mv<0x142>(v); v=v>o?v:o;   // row_bcast:15
  o=dpp_mv<0x143>(v); v=v>o?v:o;   // row_bcast:31
  return (unsigned)__builtin_amdgcn_readlane((int)v, 63);
}
__device__ __forceinline__ unsigned wave_umin_b(unsigned v){
  unsigned o;
  o=dpp_mv<0x111>(v); v=v<o?v:o;
  o=dpp_mv<0x112>(v); v=v<o?v:o;
  o=dpp_mv<0x114>(v); v=v<o?v:o;
  o=dpp_mv<0x118>(v); v=v<o?v:o;
  o=dpp_mv<0x142>(v); v=v<o?v:o;
  o=dpp_mv<0x143>(v); v=v<o?v:o;
  return (unsigned)__builtin_amdgcn_readlane((int)v, 63);
}

// ---------------------------------------------------------------- FPS
// R12/R14 FROZEN version (623-627 µs, measured 5×): 4 waves, s_barrier per
// iter, two-phase u32 DPP argmax, winner coords via uniform broadcast LDS read.
// Failed variants (do not redo): 8-wave (R16, +64), LDS spin-poll (R15, +156),
// merged u64 chain + coord-carry slots (R19, +37).
__global__ __launch_bounds__(256) void k_fps(const float* __restrict__ xyz,
                                             float* __restrict__ cxyz){
  const int b = blockIdx.x, tid = threadIdx.x;
  const int wave = tid>>6, lane = tid&63;
  const float* X = xyz + (size_t)b*NPTS*3;
  __shared__ float Xl[NPTS*3];
  __shared__ float Cl[SCTR*3];
  __shared__ unsigned long long slot[2][4];
  for(int i=tid;i<NPTS*3;i+=256) Xl[i]=X[i];
  __syncthreads();
  float px[16],py[16],pz[16],mind[16];
  const float c0x=Xl[0], c0y=Xl[1], c0z=Xl[2];
#pragma unroll
  for(int t=0;t<16;t++){
    const int j = lane + 64*(wave*16+t);
    px[t]=Xl[j*3]; py[t]=Xl[j*3+1]; pz[t]=Xl[j*3+2];
    mind[t]=sq3x(fsubx(px[t],c0x), fsubx(py[t],c0y), fsubx(pz[t],c0z));
  }
  if(tid==0){ Cl[0]=c0x; Cl[1]=c0y; Cl[2]=c0z; }
  float bv=-1.0f; int bj=0x7fffffff;
#pragma unroll
  for(int t=0;t<16;t++){
    const int j = lane + 64*(wave*16+t);
    if(mind[t]>bv){ bv=mind[t]; bj=j; }
  }
  for(int it=1; it<SCTR; ++it){
    const unsigned uv = __float_as_uint(bv);
    const unsigned M  = wave_umax_b(uv);
    const unsigned nj = (uv == M) ? ~(unsigned)bj : 0u;
    const unsigned NJ = wave_umax_b(nj);
    if(lane==0) slot[it&1][wave] = ((unsigned long long)M<<32) | NJ;
    __syncthreads();          // parity double-buffer prevents WAR
    unsigned long long k0=slot[it&1][0], k1=slot[it&1][1],
                       k2=slot[it&1][2], k3=slot[it&1][3];
    unsigned long long ka = k0>k1?k0:k1;
    unsigned long long kb = k2>k3?k2:k3;
    unsigned long long kw = ka>kb?ka:kb;
    const int w = (int)(~(unsigned)kw);          // j < 4096
    const float cx=Xl[w*3], cy=Xl[w*3+1], cz=Xl[w*3+2];
    if(tid==0){ Cl[it*3]=cx; Cl[it*3+1]=cy; Cl[it*3+2]=cz; }
    bv=-1.0f; bj=0x7fffffff;
#pragma unroll
    for(int t=0;t<16;t++){
      float d = sq3x(fsubx(px[t],cx), fsubx(py[t],cy), fsubx(pz[t],cz));
      float nm = fminf(mind[t], d);
      mind[t]=nm;
      const int j = lane + 64*(wave*16+t);
      if(nm>bv){ bv=nm; bj=j; }
    }
  }
  __syncthreads();
  float* O = cxyz + (size_t)b*SCTR*3;
  for(int i=tid;i<SCTR*3;i+=256) O[i]=Cl[i];
}

// ------------------------------------------- 32-NN select
// R20: octant-cached selection (evolves R16's proven quarter-cache).
// Per round the winner-rescan dominates issue cost (exec-masked but issued
// by all 64 lanes). 8 octants of 8 halve the rescan; the `taken` bitmask is
// replaced by permanently overwriting the removed element with a sentinel
// (3.0e38 > any real d ≤ 3) — all register indices remain compile-time
// (rule #20). Tie-break (ascending strict <, then min-j via jc) identical
// to the proven quarter version → bit-identical gidx.
__global__ __launch_bounds__(256) void k_select(const float* __restrict__ xyz,
                                                const float* __restrict__ cxyz,
                                                int* __restrict__ gidx){
  const int lane = threadIdx.x & 63;
  const int cid  = blockIdx.x*4 + (threadIdx.x>>6);
  const int b = cid>>10;
  const float* X = xyz + (size_t)b*NPTS*3;
  const float* C = cxyz + (size_t)cid*3;
  const float cx=C[0], cy=C[1], cz=C[2];
  const float a2 = sq3x(cx,cy,cz);
  float d[64];
#pragma unroll
  for(int t=0;t<64;t++){
    int j = lane + (t<<6);
    float x=X[j*3], y=X[j*3+1], z=X[j*3+2];
    float b2 = sq3x(x,y,z);
    float dt = dot3fma(cx,cy,cz, x,y,z);
    float dd = fsubx(faddx(a2,b2), fmulx(2.0f,dt));
    d[t] = fmaxf(dd, 0.0f);
  }
  // per-octant (8-elem) cached minima — strict <, ascending t → smallest-t ties
  float qv[8]; int qt[8];
#pragma unroll
  for(int o=0;o<8;o++){ qv[o]=3.0e38f; qt[o]=o*8; }
#pragma unroll
  for(int o=0;o<8;o++){
#pragma unroll
    for(int k=0;k<8;k++){
      if(d[o*8+k] < qv[o]){ qv[o]=d[o*8+k]; qt[o]=o*8+k; }
    }
  }
  int* out = gidx + (size_t)cid*KNN;
#pragma unroll 1
  for(int r=0;r<KNN;r++){
    // lane-best among 8 octant candidates (ascending strict < → smallest t)
    float mv = qv[0]; int mt = qt[0];
#pragma unroll
    for(int o=1;o<8;o++){ if(qv[o] < mv){ mv=qv[o]; mt=qt[o]; } }
    const unsigned um = __float_as_uint(mv);   // d >= 0 → bit order = value order
    const unsigned Mw = wave_umin_b(um);
    const unsigned jc = (um == Mw) ? (unsigned)(lane + (mt<<6)) : 0xffffffffu;
    const unsigned WJ = wave_umin_b(jc);
    const int wl = (int)(WJ & 63u);
    const int wt = (int)(WJ >> 6);
    if(lane == wl) out[r] = (int)WJ;
    // rescan ONLY the winner's octant; wo is wave-uniform (WJ broadcast).
    // Removed element is overwritten with the sentinel (static index per k2).
    const int wo = wt >> 3;
#define RESCAN_O(O) \
    if(lane == wl){ \
      float nv=3.0e38f; int nt=(O)*8; \
      _Pragma("unroll") \
      for(int k2=0;k2<8;k2++){ \
        float dv = d[(O)*8+k2]; \
        if((O)*8+k2 == wt){ dv = 3.0e38f; d[(O)*8+k2] = 3.0e38f; } \
        if(dv < nv){ nv=dv; nt=(O)*8+k2; } \
      } \
      qv[O]=nv; qt[O]=nt; \
    }
    switch(wo){
      case 0: RESCAN_O(0) break;
      case 1: RESCAN_O(1) break;
      case 2: RESCAN_O(2) break;
      case 3: RESCAN_O(3) break;
      case 4: RESCAN_O(4) break;
      case 5: RESCAN_O(5) break;
      case 6: RESCAN_O(6) break;
      default: RESCAN_O(7) break;
    }
#undef RESCAN_O
  }
}

// ------------------------------------------------- shared tile helpers
__device__ __forceinline__ void stage_in(float* INt, int rbase,
                                         const float* __restrict__ xyz,
                                         const float* __restrict__ feat,
                                         const float* __restrict__ cxyz,
                                         const int* __restrict__ gidx){
  const int tid = threadIdx.x;
  const int row = tid>>2, sub = tid&3;
  const int r  = rbase + row;
  const int bb = r>>15, ss=(r>>5)&1023;
  const int idx = gidx[r];
  if(sub==0){
    const float* P = xyz  + ((size_t)bb*NPTS + idx)*3;
    const float* C = cxyz + ((size_t)(bb*SCTR)+ss)*3;
    INt[0*68+row] = P[0]-C[0];
    INt[1*68+row] = P[1]-C[1];
    INt[2*68+row] = P[2]-C[2];
  }else{
    const float* F = feat + ((size_t)bb*NPTS + idx)*6;
    const int c = (sub-1)*2;
    INt[(3+c)*68+row] = F[c];
    INt[(4+c)*68+row] = F[c+1];
  }
}

__device__ __forceinline__ void gemm1(const float* INt, const float* __restrict__ W1,
                                      int rt, int ct, float acc[4][4]){
#pragma unroll
  for(int i=0;i<4;i++)
#pragma unroll
    for(int j=0;j<4;j++) acc[i][j]=0.f;
#pragma unroll
  for(int c=0;c<9;c++){
    const float4 a = *(const float4*)&INt[c*68 + rt*4];
    const float4 w = *(const float4*)&W1[c*64 + ct*4];
    const float av[4]={a.x,a.y,a.z,a.w}, wv[4]={w.x,w.y,w.z,w.w};
#pragma unroll
    for(int i=0;i<4;i++)
#pragma unroll
      for(int j=0;j<4;j++) acc[i][j] += av[i]*wv[j];
  }
}

// fold one channel across the NREP replicated copies
__device__ __forceinline__ float fold_rep(const float* __restrict__ pstats, int off){
  float s=0.f;
#pragma unroll 8
  for(int c=0;c<NREP;c++) s += pstats[c*512 + off];
  return s;
}

// -------------------------------------- BN affine coef precompute (R17, ~−21µs)
// Hoists the 64-replica fold + rsqrt OUT of the 8192 consumer blocks.
// Fold order is the SAME fold_rep → coefficients are bit-identical.
__global__ __launch_bounds__(64) void k_coef(const float* __restrict__ pstats,
                                             const float* __restrict__ g,
                                             const float* __restrict__ b,
                                             float* __restrict__ coefo,
                                             int off){
  const int t = threadIdx.x;   // 64
  float sm = fold_rep(pstats, off+t);
  float sq = fold_rep(pstats, off+64+t);
  float m  = sm/RNF;
  float vv = sq/RNF - m*m;
  float A  = rsqrtf(vv+EPSV)*g[t];
  coefo[t]    = A;
  coefo[64+t] = b[t]-m*A;
}

// ---------------------------------------------------------------- layer-1 stats
// Epilogue: R1-proven LDS atomicAdd form (R17's DPP epilogue spilled — see top).
__global__ __launch_bounds__(256) void k_stats1(const float* __restrict__ xyz,
                                                const float* __restrict__ feat,
                                                const float* __restrict__ cxyz,
                                                const int* __restrict__ gidx,
                                                const float* __restrict__ W1,
                                                float* __restrict__ pstats){
  __shared__ __align__(16) float INt[9*68];
  __shared__ float sb[64], qb[64];
  const int tid=threadIdx.x;
  if(tid<64){ sb[tid]=0.f; qb[tid]=0.f; }
  stage_in(INt, blockIdx.x*64, xyz, feat, cxyz, gidx);
  __syncthreads();
  const int rt=tid&15, ct=tid>>4;
  float acc[4][4];
  gemm1(INt, W1, rt, ct, acc);
#pragma unroll
  for(int j=0;j<4;j++){
    float s=0.f, q=0.f;
#pragma unroll
    for(int i=0;i<4;i++){ float v=acc[i][j]; s+=v; q+=v*v; }
    atomicAdd(&sb[ct*4+j], s); atomicAdd(&qb[ct*4+j], q);
  }
  __syncthreads();
  if(tid<64){
    float* ps = pstats + (size_t)(blockIdx.x & (NREP-1))*512;
    atomicAdd(&ps[tid], sb[tid]); atomicAdd(&ps[64+tid], qb[tid]);
  }
}

// -------------------------------------- layer-2 stats core (optionally writes Z2)
template<bool WRITEZ>
__device__ __forceinline__ void stats2_body(const float* xyz, const float* feat,
                                            const float* cxyz, const int* gidx,
                                            const float* W1,
                                            const float* __restrict__ coef,
                                            const float* __restrict__ W2,
                                            float* pstats, float* Z2){
  __shared__ __align__(16) float INt[9*68];
  __shared__ __align__(16) float A1t[64*68];
  __shared__ float af1A[64], af1B[64];
  __shared__ float sb[64], qb[64];
  const int tid=threadIdx.x;
  if(tid<64){
    af1A[tid]=coef[tid]; af1B[tid]=coef[64+tid];
    sb[tid]=0.f; qb[tid]=0.f;
  }
  stage_in(INt, blockIdx.x*64, xyz, feat, cxyz, gidx);
  __syncthreads();
  const int rt=tid&15, ct=tid>>4;
  float acc1[4][4];
  gemm1(INt, W1, rt, ct, acc1);
#pragma unroll
  for(int j=0;j<4;j++){
    const int o=ct*4+j; const float A=af1A[o], Bc=af1B[o];
#pragma unroll
    for(int i=0;i<4;i++) A1t[o*68 + rt*4+i] = fmaxf(acc1[i][j]*A+Bc, 0.f);
  }
  __syncthreads();
  float acc2[4][4];
#pragma unroll
  for(int i=0;i<4;i++)
#pragma unroll
    for(int j=0;j<4;j++) acc2[i][j]=0.f;
#pragma unroll
  for(int c=0;c<64;c++){
    const float4 a = *(const float4*)&A1t[c*68 + rt*4];
    const float4 w = *(const float4*)&W2[c*64 + ct*4];
    const float av[4]={a.x,a.y,a.z,a.w}, wv[4]={w.x,w.y,w.z,w.w};
#pragma unroll
    for(int i=0;i<4;i++)
#pragma unroll
      for(int j=0;j<4;j++) acc2[i][j] += av[i]*wv[j];
  }
  if(WRITEZ){
#pragma unroll
    for(int i=0;i<4;i++){
      float4 v = make_float4(acc2[i][0],acc2[i][1],acc2[i][2],acc2[i][3]);
      *(float4*)&Z2[((size_t)blockIdx.x*64 + rt*4+i)*64 + ct*4] = v;
    }
  }
#pragma unroll
  for(int j=0;j<4;j++){
    float s=0.f, q=0.f;
#pragma unroll
    for(int i=0;i<4;i++){ float v=acc2[i][j]; s+=v; q+=v*v; }
    atomicAdd(&sb[ct*4+j], s); atomicAdd(&qb[ct*4+j], q);
  }
  __syncthreads();
  if(tid<64){
    float* ps = pstats + (size_t)(blockIdx.x & (NREP-1))*512;
    atomicAdd(&ps[128+tid], sb[tid]); atomicAdd(&ps[192+tid], qb[tid]);
  }
}

__global__ __launch_bounds__(256) void k_stats2(const float* __restrict__ xyz,
                                                const float* __restrict__ feat,
                                                const float* __restrict__ cxyz,
                                                const int* __restrict__ gidx,
                                                const float* __restrict__ W1,
                                                const float* __restrict__ coef,
                                                const float* __restrict__ W2,
                                                float* __restrict__ pstats){
  stats2_body<false>(xyz,feat,cxyz,gidx,W1,coef,W2,pstats,nullptr);
}
__global__ __launch_bounds__(256) void k_stats2m(const float* __restrict__ xyz,
                                                 const float* __restrict__ feat,
                                                 const float* __restrict__ cxyz,
                                                 const int* __restrict__ gidx,
                                                 const float* __restrict__ W1,
                                                 const float* __restrict__ coef,
                                                 const float* __restrict__ W2,
                                                 float* __restrict__ pstats,
                                                 float* __restrict__ Z2){
  stats2_body<true>(xyz,feat,cxyz,gidx,W1,coef,W2,pstats,Z2);
}

// ------------------------------------------- layer-3 (fallback: full recompute)
__global__ __launch_bounds__(256) void k_layer3(const float* __restrict__ xyz,
                                                const float* __restrict__ feat,
                                                const float* __restrict__ cxyz,
                                                const int* __restrict__ gidx,
                                                const float* __restrict__ W1,
                                                const float* __restrict__ coef,
                                                const float* __restrict__ W2,
                                                const float* __restrict__ W3,
                                                float* __restrict__ pstats,
                                                float* __restrict__ premax){
  __shared__ __align__(16) float INt[9*68];
  __shared__ __align__(16) float A1t[64*68];
  __shared__ float af1A[64], af1B[64], af2A[64], af2B[64];
  __shared__ unsigned mx[256];
  __shared__ float s3b[256], q3b[256];
  const int tid=threadIdx.x;
  if(tid<64){
    af1A[tid]=coef[tid];     af1B[tid]=coef[64+tid];
    af2A[tid]=coef[128+tid]; af2B[tid]=coef[192+tid];
  }
  mx[tid]=0u; s3b[tid]=0.f; q3b[tid]=0.f;
  stage_in(INt, blockIdx.x*64, xyz, feat, cxyz, gidx);
  __syncthreads();
  const int rt=tid&15, ct=tid>>4;
  float acc1[4][4];
  gemm1(INt, W1, rt, ct, acc1);
#pragma unroll
  for(int j=0;j<4;j++){
    const int o=ct*4+j; const float A=af1A[o], Bc=af1B[o];
#pragma unroll
    for(int i=0;i<4;i++) A1t[o*68 + rt*4+i] = fmaxf(acc1[i][j]*A+Bc, 0.f);
  }
  __syncthreads();
  float acc2[4][4];
#pragma unroll
  for(int i=0;i<4;i++)
#pragma unroll
    for(int j=0;j<4;j++) acc2[i][j]=0.f;
#pragma unroll
  for(int c=0;c<64;c++){
    const float4 a = *(const float4*)&A1t[c*68 + rt*4];
    const float4 w = *(const float4*)&W2[c*64 + ct*4];
    const float av[4]={a.x,a.y,a.z,a.w}, wv[4]={w.x,w.y,w.z,w.w};
#pragma unroll
    for(int i=0;i<4;i++)
#pragma unroll
      for(int j=0;j<4;j++) acc2[i][j] += av[i]*wv[j];
  }
  float a2v[4][4];
#pragma unroll
  for(int j=0;j<4;j++){
    const int o=ct*4+j; const float A=af2A[o], Bc=af2B[o];
#pragma unroll
    for(int i=0;i<4;i++) a2v[i][j]=fmaxf(acc2[i][j]*A+Bc, 0.f);
  }
  __syncthreads();
#pragma unroll
  for(int j=0;j<4;j++)
#pragma unroll
    for(int i=0;i<4;i++) A1t[(ct*4+j)*68 + rt*4+i] = a2v[i][j];
  __syncthreads();
  float acc3[4][8];
#pragma unroll
  for(int i=0;i<4;i++)
#pragma unroll
    for(int j=0;j<8;j++) acc3[i][j]=0.f;
#pragma unroll
  for(int c=0;c<64;c++){
    const float4 a  = *(const float4*)&A1t[c*68 + rt*4];
    const float4 w0 = *(const float4*)&W3[c*128 + ct*8];
    const float4 w1 = *(const float4*)&W3[c*128 + ct*8 + 4];
    const float av[4]={a.x,a.y,a.z,a.w};
    const float wv[8]={w0.x,w0.y,w0.z,w0.w,w1.x,w1.y,w1.z,w1.w};
#pragma unroll
    for(int i=0;i<4;i++)
#pragma unroll
      for(int j=0;j<8;j++) acc3[i][j] += av[i]*wv[j];
  }
  const int g = rt>>3;
#pragma unroll
  for(int j=0;j<8;j++){
    const int o=ct*8+j;
    float lm=acc3[0][j], s=0.f, q=0.f;
#pragma unroll
    for(int i=0;i<4;i++){ float v=acc3[i][j]; lm=fmaxf(lm,v); s+=v; q+=v*v; }
    atomicMax(&mx[g*128+o], fkey(lm));
    atomicAdd(&s3b[g*128+o], s);
    atomicAdd(&q3b[g*128+o], q);
  }
  __syncthreads();
  {
    const int gg=tid>>7, o=tid&127;
    const int cid = blockIdx.x*2+gg;
    premax[(size_t)cid*128+o] = funkey(mx[tid]);
  }
  if(tid<128){
    float* ps = pstats + (size_t)(blockIdx.x & (NREP-1))*512;
    atomicAdd(&ps[256+tid], s3b[tid]+s3b[128+tid]);
    atomicAdd(&ps[384+tid], q3b[tid]+q3b[128+tid]);
  }
}

// ------------------------------------------- layer-3 LEAN: reads materialized Z2
__global__ __launch_bounds__(256) void k_layer3z(const float* __restrict__ Z2,
                                                 const float* __restrict__ coef,
                                                 const float* __restrict__ W3,
                                                 float* __restrict__ pstats,
                                                 float* __restrict__ premax){
  __shared__ __align__(16) float A2t[64*68];
  __shared__ float af2A[64], af2B[64];
  __shared__ unsigned mx[256];
  __shared__ float s3b[256], q3b[256];
  const int tid=threadIdx.x;
  if(tid<64){
    af2A[tid]=coef[128+tid]; af2B[tid]=coef[192+tid];
  }
  mx[tid]=0u; s3b[tid]=0.f; q3b[tid]=0.f;
  __syncthreads();
  {
    const int row = tid>>2, cq = (tid&3)*16;
    const float* zr = Z2 + ((size_t)blockIdx.x*64 + row)*64 + cq;
    const float4 z0 = *(const float4*)(zr);
    const float4 z1 = *(const float4*)(zr+4);
    const float4 z2 = *(const float4*)(zr+8);
    const float4 z3 = *(const float4*)(zr+12);
    const float zz[16]={z0.x,z0.y,z0.z,z0.w, z1.x,z1.y,z1.z,z1.w,
                        z2.x,z2.y,z2.z,z2.w, z3.x,z3.y,z3.z,z3.w};
#pragma unroll
    for(int u=0;u<16;u++){
      const int c = cq+u;
      A2t[c*68+row] = fmaxf(zz[u]*af2A[c]+af2B[c], 0.f);
    }
  }
  __syncthreads();
  const int rt=tid&15, ct=tid>>4;
  float acc3[4][8];
#pragma unroll
  for(int i=0;i<4;i++)
#pragma unroll
    for(int j=0;j<8;j++) acc3[i][j]=0.f;
#pragma unroll
  for(int c=0;c<64;c++){
    const float4 a  = *(const float4*)&A2t[c*68 + rt*4];
    const float4 w0 = *(const float4*)&W3[c*128 + ct*8];
    const float4 w1 = *(const float4*)&W3[c*128 + ct*8 + 4];
    const float av[4]={a.x,a.y,a.z,a.w};
    const float wv[8]={w0.x,w0.y,w0.z,w0.w,w1.x,w1.y,w1.z,w1.w};
#pragma unroll
    for(int i=0;i<4;i++)
#pragma unroll
      for(int j=0;j<8;j++) acc3[i][j] += av[i]*wv[j];
  }
  const int g = rt>>3;
#pragma unroll
  for(int j=0;j<8;j++){
    const int o=ct*8+j;
    float lm=acc3[0][j], s=0.f, q=0.f;
#pragma unroll
    for(int i=0;i<4;i++){ float v=acc3[i][j]; lm=fmaxf(lm,v); s+=v; q+=v*v; }
    atomicMax(&mx[g*128+o], fkey(lm));
    atomicAdd(&s3b[g*128+o], s);
    atomicAdd(&q3b[g*128+o], q);
  }
  __syncthreads();
  {
    const int gg=tid>>7, o=tid&127;
    const int cid = blockIdx.x*2+gg;
    premax[(size_t)cid*128+o] = funkey(mx[tid]);
  }
  if(tid<128){
    float* ps = pstats + (size_t)(blockIdx.x & (NREP-1))*512;
    atomicAdd(&ps[256+tid], s3b[tid]+s3b[128+tid]);
    atomicAdd(&ps[384+tid], q3b[tid]+q3b[128+tid]);
  }
}

// ------------------------------------------- fold layer-3 partials -> cstats
__global__ __launch_bounds__(256) void k_red3(const float* __restrict__ pstats,
                                              float* __restrict__ cstats){
  const int t = threadIdx.x;   // 256: [0..127]=sums, [128..255]=sumsq
  cstats[t] = fold_rep(pstats, 256+t);
}

// ------------------------------------------- final BN+relu (in place on outf)
__global__ __launch_bounds__(256) void k_final(const float* __restrict__ cstats,
                                               const float* __restrict__ g3,
                                               const float* __restrict__ b3,
                                               float* __restrict__ outf){
  const int i = blockIdx.x*256 + threadIdx.x;
  const int o = i & 127;
  float m  = cstats[o]/RNF;
  float vv = cstats[128+o]/RNF - m*m;
  float A  = rsqrtf(vv+EPSV)*g3[o];
  float Bc = b3[o]-m*A;
  float v  = outf[i];
  outf[i] = fmaxf(v*A+Bc, 0.f);
}

extern "C" void kernel_launch(void* const* d_in, const int* in_sizes, int n_in,
                              void* d_out, int out_size, void* d_ws, size_t ws_size,
                              hipStream_t stream){
  const float* xyz  = (const float*)d_in[0];
  const float* feat = (const float*)d_in[1];
  const float* W1   = (const float*)d_in[2];
  const float* g1   = (const float*)d_in[3];
  const float* b1   = (const float*)d_in[4];
  const float* W2   = (const float*)d_in[5];
  const float* g2   = (const float*)d_in[6];
  const float* b2   = (const float*)d_in[7];
  const float* W3   = (const float*)d_in[8];
  const float* g3   = (const float*)d_in[9];
  const float* b3   = (const float*)d_in[10];
  float* out  = (float*)d_out;
  float* cxyz = out;                     // (16,1024,3)
  float* outf = out + 16*1024*3;         // (16,1024,128) — premax staging then final
  // ws layout: [pstats 64x512 f32 @0 (128KB)][cstats 256 f32 @131072]
  //            [coef 256 f32 @132096: A1,B1,A2,B2][gidx 2MB @133120]
  //            [Z2 134MB @2230272 (fast path)]
  float* pstats = (float*)d_ws;
  float* cstats = (float*)((char*)d_ws + 131072);
  float* coef   = (float*)((char*)d_ws + 132096);
  int*   gidx   = (int*)((char*)d_ws + 133120);
  float* Z2     = (float*)((char*)d_ws + 133120 + (size_t)RTOT*4);
  const size_t need = 133120 + (size_t)RTOT*4 + (size_t)RTOT*64*4;  // ≈136.4 MB
  const bool fast = (ws_size >= need);   // ws_size constant per harness → same path every call

  hipMemsetAsync(pstats, 0, (size_t)NREP*512*sizeof(float), stream);
  k_fps   <<<16,   256,  0, stream>>>(xyz, cxyz);
  k_select<<<4096, 256,  0, stream>>>(xyz, cxyz, gidx);
  k_stats1<<<8192, 256,  0, stream>>>(xyz, feat, cxyz, gidx, W1, pstats);
  k_coef  <<<1,    64,   0, stream>>>(pstats, g1, b1, coef, 0);        // A1,B1
  if(fast){
    k_stats2m<<<8192, 256, 0, stream>>>(xyz, feat, cxyz, gidx, W1, coef, W2, pstats, Z2);
    k_coef  <<<1,    64,  0, stream>>>(pstats, g2, b2, coef+128, 128); // A2,B2
    k_layer3z<<<8192, 256, 0, stream>>>(Z2, coef, W3, pstats, outf);
  }else{
    k_stats2 <<<8192, 256, 0, stream>>>(xyz, feat, cxyz, gidx, W1, coef, W2, pstats);
    k_coef  <<<1,    64,  0, stream>>>(pstats, g2, b2, coef+128, 128); // A2,B2
    k_layer3 <<<8192, 256, 0, stream>>>(xyz, feat, cxyz, gidx, W1, coef, W2, W3, pstats, outf);
  }
  k_red3  <<<1,    256,  0, stream>>>(pstats, cstats);
  k_final <<<8192, 256,  0, stream>>>(cstats, g3, b3, outf);
}

// Round 7
// 1474.326 us; speedup vs baseline: 1.0582x; 1.0582x over previous
//
#include <hip/hip_runtime.h>

#define BN_   16
#define NPTS  4096
#define DFEAT 6
#define SCTR  1024
#define KNN   32
#define RTOT  (BN_*SCTR*KNN)   /* 524288 rows */
#define EPSV  1e-5f
#define RNF   524288.0f
#define NREP  64               /* replicated stats copies */

__device__ __forceinline__ float fmulx(float a, float b){ return __fmul_rn(a,b); }
__device__ __forceinline__ float faddx(float a, float b){ return __fadd_rn(a,b); }
__device__ __forceinline__ float fsubx(float a, float b){ return __fsub_rn(a,b); }
// naive (non-FMA) sum of squares — LOCKED by R5/R6 pass.
__device__ __forceinline__ float sq3x(float x, float y, float z){
  return faddx(faddx(fmulx(x,x), fmulx(y,y)), fmulx(z,z));
}
// FMA-contracted inner product (matches np einsum) — LOCKED by R5 pass.
__device__ __forceinline__ float dot3fma(float ax, float ay, float az,
                                         float bx, float by, float bz){
  return __fmaf_rn(az, bz, __fmaf_rn(ay, by, __fmul_rn(ax, bx)));
}

__device__ __forceinline__ unsigned fkey(float f){
  unsigned u = __float_as_uint(f);
  return (u & 0x80000000u) ? ~u : (u | 0x80000000u);
}
__device__ __forceinline__ float funkey(unsigned k){
  return (k & 0x80000000u) ? __uint_as_float(k & 0x7fffffffu) : __uint_as_float(~k);
}

// ---------------- DPP wave64 reductions (VALU-only; proven on HW in R12).
// R17 POST-MORTEM: DPP row-sum chains in wide-unrolled stats EPILOGUES spill
// (VGPR=256, 9.7 GB scratch HBM). DPP stays ONLY in argmax reductions.
// R19 POST-MORTEM: merged u64 (value,~j) DPP chain is NOT cheaper than two
// u32 chains — REGRESSED +37 µs. k_fps is FROZEN at the R12/R14 form.
// R20 POST-MORTEM: octant-cached select with qv[8]/qt[8] arrays + 8-way
// switch REGRESSED ~90 µs vs quarter-cache with NAMED SCALARS (q0v..q3v) —
// array-in-branchy-joins demotes to scratch. k_select FROZEN at quarter form.
template<int CTRL>
__device__ __forceinline__ unsigned dpp_mv(unsigned v){
  return (unsigned)__builtin_amdgcn_update_dpp((int)v, (int)v, CTRL, 0xf, 0xf, false);
}
__device__ __forceinline__ unsigned wave_umax_b(unsigned v){
  unsigned o;
  o=dpp_mv<0x111>(v); v=v>o?v:o;   // row_shr:1
  o=dpp_mv<0x112>(v); v=v>o?v:o;   // row_shr:2
  o=dpp_mv<0x114>(v); v=v>o?v:o;   // row_shr:4
  o=dpp_mv<0x118>(v); v=v>o?v:o;   // row_shr:8
  o=dpp_mv<0x142>(v); v=v>o?v:o;   // row_bcast:15
  o=dpp_mv<0x143>(v); v=v>o?v:o;   // row_bcast:31
  return (unsigned)__builtin_amdgcn_readlane((int)v, 63);
}
__device__ __forceinline__ unsigned wave_umin_b(unsigned v){
  unsigned o;
  o=dpp_mv<0x111>(v); v=v<o?v:o;
  o=dpp_mv<0x112>(v); v=v<o?v:o;
  o=dpp_mv<0x114>(v); v=v<o?v:o;
  o=dpp_mv<0x118>(v); v=v<o?v:o;
  o=dpp_mv<0x142>(v); v=v<o?v:o;
  o=dpp_mv<0x143>(v); v=v<o?v:o;
  return (unsigned)__builtin_amdgcn_readlane((int)v, 63);
}

// ---------------------------------------------------------------- FPS
// R12/R14 FROZEN version (623-627 µs, measured 8×): 4 waves, s_barrier per
// iter, two-phase u32 DPP argmax, winner coords via uniform broadcast LDS read.
// Failed variants (do not redo): 8-wave (R16, +64), LDS spin-poll (R15, +156),
// merged u64 chain + coord-carry slots (R19, +37).
__global__ __launch_bounds__(256) void k_fps(const float* __restrict__ xyz,
                                             float* __restrict__ cxyz){
  const int b = blockIdx.x, tid = threadIdx.x;
  const int wave = tid>>6, lane = tid&63;
  const float* X = xyz + (size_t)b*NPTS*3;
  __shared__ float Xl[NPTS*3];
  __shared__ float Cl[SCTR*3];
  __shared__ unsigned long long slot[2][4];
  for(int i=tid;i<NPTS*3;i+=256) Xl[i]=X[i];
  __syncthreads();
  float px[16],py[16],pz[16],mind[16];
  const float c0x=Xl[0], c0y=Xl[1], c0z=Xl[2];
#pragma unroll
  for(int t=0;t<16;t++){
    const int j = lane + 64*(wave*16+t);
    px[t]=Xl[j*3]; py[t]=Xl[j*3+1]; pz[t]=Xl[j*3+2];
    mind[t]=sq3x(fsubx(px[t],c0x), fsubx(py[t],c0y), fsubx(pz[t],c0z));
  }
  if(tid==0){ Cl[0]=c0x; Cl[1]=c0y; Cl[2]=c0z; }
  float bv=-1.0f; int bj=0x7fffffff;
#pragma unroll
  for(int t=0;t<16;t++){
    const int j = lane + 64*(wave*16+t);
    if(mind[t]>bv){ bv=mind[t]; bj=j; }
  }
  for(int it=1; it<SCTR; ++it){
    const unsigned uv = __float_as_uint(bv);
    const unsigned M  = wave_umax_b(uv);
    const unsigned nj = (uv == M) ? ~(unsigned)bj : 0u;
    const unsigned NJ = wave_umax_b(nj);
    if(lane==0) slot[it&1][wave] = ((unsigned long long)M<<32) | NJ;
    __syncthreads();          // parity double-buffer prevents WAR
    unsigned long long k0=slot[it&1][0], k1=slot[it&1][1],
                       k2=slot[it&1][2], k3=slot[it&1][3];
    unsigned long long ka = k0>k1?k0:k1;
    unsigned long long kb = k2>k3?k2:k3;
    unsigned long long kw = ka>kb?ka:kb;
    const int w = (int)(~(unsigned)kw);          // j < 4096
    const float cx=Xl[w*3], cy=Xl[w*3+1], cz=Xl[w*3+2];
    if(tid==0){ Cl[it*3]=cx; Cl[it*3+1]=cy; Cl[it*3+2]=cz; }
    bv=-1.0f; bj=0x7fffffff;
#pragma unroll
    for(int t=0;t<16;t++){
      float d = sq3x(fsubx(px[t],cx), fsubx(py[t],cy), fsubx(pz[t],cz));
      float nm = fminf(mind[t], d);
      mind[t]=nm;
      const int j = lane + 64*(wave*16+t);
      if(nm>bv){ bv=nm; bj=j; }
    }
  }
  __syncthreads();
  float* O = cxyz + (size_t)b*SCTR*3;
  for(int i=tid;i<SCTR*3;i+=256) O[i]=Cl[i];
}

// ------------------------------------------- 32-NN select
// R16/R18 FROZEN quarter-cached version (proven 1470 µs config, measured
// with it twice). NAMED SCALAR candidates q0v..q3v — do NOT convert to
// arrays (R20: octant arrays + switch = +90 µs scratch-demotion regression).
__global__ __launch_bounds__(256) void k_select(const float* __restrict__ xyz,
                                                const float* __restrict__ cxyz,
                                                int* __restrict__ gidx){
  const int lane = threadIdx.x & 63;
  const int cid  = blockIdx.x*4 + (threadIdx.x>>6);
  const int b = cid>>10;
  const float* X = xyz + (size_t)b*NPTS*3;
  const float* C = cxyz + (size_t)cid*3;
  const float cx=C[0], cy=C[1], cz=C[2];
  const float a2 = sq3x(cx,cy,cz);
  float d[64];
#pragma unroll
  for(int t=0;t<64;t++){
    int j = lane + (t<<6);
    float x=X[j*3], y=X[j*3+1], z=X[j*3+2];
    float b2 = sq3x(x,y,z);
    float dt = dot3fma(cx,cy,cz, x,y,z);
    float dd = fsubx(faddx(a2,b2), fmulx(2.0f,dt));
    d[t] = fmaxf(dd, 0.0f);
  }
  float q0v=3.0e38f, q1v=3.0e38f, q2v=3.0e38f, q3v=3.0e38f;
  int   q0t=0, q1t=16, q2t=32, q3t=48;
#pragma unroll
  for(int k=0;k<16;k++){ if(d[k]    < q0v){ q0v=d[k];    q0t=k;    } }
#pragma unroll
  for(int k=0;k<16;k++){ if(d[16+k] < q1v){ q1v=d[16+k]; q1t=16+k; } }
#pragma unroll
  for(int k=0;k<16;k++){ if(d[32+k] < q2v){ q2v=d[32+k]; q2t=32+k; } }
#pragma unroll
  for(int k=0;k<16;k++){ if(d[48+k] < q3v){ q3v=d[48+k]; q3t=48+k; } }
  unsigned long long taken = 0ull;
  int* out = gidx + (size_t)cid*KNN;
#pragma unroll 1
  for(int r=0;r<KNN;r++){
    float mv = q0v; int mt = q0t;
    if(q1v < mv){ mv=q1v; mt=q1t; }
    if(q2v < mv){ mv=q2v; mt=q2t; }
    if(q3v < mv){ mv=q3v; mt=q3t; }
    const unsigned um = __float_as_uint(mv);   // d >= 0 → bit order = value order
    const unsigned Mw = wave_umin_b(um);
    const unsigned jc = (um == Mw) ? (unsigned)(lane + (mt<<6)) : 0xffffffffu;
    const unsigned WJ = wave_umin_b(jc);
    const int wl = (int)(WJ & 63u);
    const int wt = (int)(WJ >> 6);
    if(lane == wl){
      out[r] = (int)WJ;
      taken |= (1ull << wt);
    }
    const int wq = wt >> 4;
#define RESCAN_Q(QV,QT,BASE) \
    if(lane == wl){ \
      float nv=3.0e38f; int nt=BASE; \
      _Pragma("unroll") \
      for(int k2=0;k2<16;k2++){ \
        if(!(taken & (1ull<<(BASE+k2))) && d[BASE+k2] < nv){ nv=d[BASE+k2]; nt=BASE+k2; } \
      } \
      QV=nv; QT=nt; \
    }
    if(wq==0)      { RESCAN_Q(q0v,q0t,0)  }
    else if(wq==1) { RESCAN_Q(q1v,q1t,16) }
    else if(wq==2) { RESCAN_Q(q2v,q2t,32) }
    else           { RESCAN_Q(q3v,q3t,48) }
#undef RESCAN_Q
  }
}

// ------------------------------------------------- shared tile helpers
__device__ __forceinline__ void stage_in(float* INt, int rbase,
                                         const float* __restrict__ xyz,
                                         const float* __restrict__ feat,
                                         const float* __restrict__ cxyz,
                                         const int* __restrict__ gidx){
  const int tid = threadIdx.x;
  const int row = tid>>2, sub = tid&3;
  const int r  = rbase + row;
  const int bb = r>>15, ss=(r>>5)&1023;
  const int idx = gidx[r];
  if(sub==0){
    const float* P = xyz  + ((size_t)bb*NPTS + idx)*3;
    const float* C = cxyz + ((size_t)(bb*SCTR)+ss)*3;
    INt[0*68+row] = P[0]-C[0];
    INt[1*68+row] = P[1]-C[1];
    INt[2*68+row] = P[2]-C[2];
  }else{
    const float* F = feat + ((size_t)bb*NPTS + idx)*6;
    const int c = (sub-1)*2;
    INt[(3+c)*68+row] = F[c];
    INt[(4+c)*68+row] = F[c+1];
  }
}

__device__ __forceinline__ void gemm1(const float* INt, const float* __restrict__ W1,
                                      int rt, int ct, float acc[4][4]){
#pragma unroll
  for(int i=0;i<4;i++)
#pragma unroll
    for(int j=0;j<4;j++) acc[i][j]=0.f;
#pragma unroll
  for(int c=0;c<9;c++){
    const float4 a = *(const float4*)&INt[c*68 + rt*4];
    const float4 w = *(const float4*)&W1[c*64 + ct*4];
    const float av[4]={a.x,a.y,a.z,a.w}, wv[4]={w.x,w.y,w.z,w.w};
#pragma unroll
    for(int i=0;i<4;i++)
#pragma unroll
      for(int j=0;j<4;j++) acc[i][j] += av[i]*wv[j];
  }
}

// fold one channel across the NREP replicated copies
__device__ __forceinline__ float fold_rep(const float* __restrict__ pstats, int off){
  float s=0.f;
#pragma unroll 8
  for(int c=0;c<NREP;c++) s += pstats[c*512 + off];
  return s;
}

// -------------------------------------- BN affine coef precompute (R17, ~−21µs)
// Hoists the 64-replica fold + rsqrt OUT of the 8192 consumer blocks.
// Fold order is the SAME fold_rep → coefficients are bit-identical.
__global__ __launch_bounds__(64) void k_coef(const float* __restrict__ pstats,
                                             const float* __restrict__ g,
                                             const float* __restrict__ b,
                                             float* __restrict__ coefo,
                                             int off){
  const int t = threadIdx.x;   // 64
  float sm = fold_rep(pstats, off+t);
  float sq = fold_rep(pstats, off+64+t);
  float m  = sm/RNF;
  float vv = sq/RNF - m*m;
  float A  = rsqrtf(vv+EPSV)*g[t];
  coefo[t]    = A;
  coefo[64+t] = b[t]-m*A;
}

// ---------------------------------------------------------------- layer-1 stats
// Epilogue: R1-proven LDS atomicAdd form (R17's DPP epilogue spilled — see top).
__global__ __launch_bounds__(256) void k_stats1(const float* __restrict__ xyz,
                                                const float* __restrict__ feat,
                                                const float* __restrict__ cxyz,
                                                const int* __restrict__ gidx,
                                                const float* __restrict__ W1,
                                                float* __restrict__ pstats){
  __shared__ __align__(16) float INt[9*68];
  __shared__ float sb[64], qb[64];
  const int tid=threadIdx.x;
  if(tid<64){ sb[tid]=0.f; qb[tid]=0.f; }
  stage_in(INt, blockIdx.x*64, xyz, feat, cxyz, gidx);
  __syncthreads();
  const int rt=tid&15, ct=tid>>4;
  float acc[4][4];
  gemm1(INt, W1, rt, ct, acc);
#pragma unroll
  for(int j=0;j<4;j++){
    float s=0.f, q=0.f;
#pragma unroll
    for(int i=0;i<4;i++){ float v=acc[i][j]; s+=v; q+=v*v; }
    atomicAdd(&sb[ct*4+j], s); atomicAdd(&qb[ct*4+j], q);
  }
  __syncthreads();
  if(tid<64){
    float* ps = pstats + (size_t)(blockIdx.x & (NREP-1))*512;
    atomicAdd(&ps[tid], sb[tid]); atomicAdd(&ps[64+tid], qb[tid]);
  }
}

// -------------------------------------- layer-2 stats core (optionally writes Z2)
template<bool WRITEZ>
__device__ __forceinline__ void stats2_body(const float* xyz, const float* feat,
                                            const float* cxyz, const int* gidx,
                                            const float* W1,
                                            const float* __restrict__ coef,
                                            const float* __restrict__ W2,
                                            float* pstats, float* Z2){
  __shared__ __align__(16) float INt[9*68];
  __shared__ __align__(16) float A1t[64*68];
  __shared__ float af1A[64], af1B[64];
  __shared__ float sb[64], qb[64];
  const int tid=threadIdx.x;
  if(tid<64){
    af1A[tid]=coef[tid]; af1B[tid]=coef[64+tid];
    sb[tid]=0.f; qb[tid]=0.f;
  }
  stage_in(INt, blockIdx.x*64, xyz, feat, cxyz, gidx);
  __syncthreads();
  const int rt=tid&15, ct=tid>>4;
  float acc1[4][4];
  gemm1(INt, W1, rt, ct, acc1);
#pragma unroll
  for(int j=0;j<4;j++){
    const int o=ct*4+j; const float A=af1A[o], Bc=af1B[o];
#pragma unroll
    for(int i=0;i<4;i++) A1t[o*68 + rt*4+i] = fmaxf(acc1[i][j]*A+Bc, 0.f);
  }
  __syncthreads();
  float acc2[4][4];
#pragma unroll
  for(int i=0;i<4;i++)
#pragma unroll
    for(int j=0;j<4;j++) acc2[i][j]=0.f;
#pragma unroll
  for(int c=0;c<64;c++){
    const float4 a = *(const float4*)&A1t[c*68 + rt*4];
    const float4 w = *(const float4*)&W2[c*64 + ct*4];
    const float av[4]={a.x,a.y,a.z,a.w}, wv[4]={w.x,w.y,w.z,w.w};
#pragma unroll
    for(int i=0;i<4;i++)
#pragma unroll
      for(int j=0;j<4;j++) acc2[i][j] += av[i]*wv[j];
  }
  if(WRITEZ){
#pragma unroll
    for(int i=0;i<4;i++){
      float4 v = make_float4(acc2[i][0],acc2[i][1],acc2[i][2],acc2[i][3]);
      *(float4*)&Z2[((size_t)blockIdx.x*64 + rt*4+i)*64 + ct*4] = v;
    }
  }
#pragma unroll
  for(int j=0;j<4;j++){
    float s=0.f, q=0.f;
#pragma unroll
    for(int i=0;i<4;i++){ float v=acc2[i][j]; s+=v; q+=v*v; }
    atomicAdd(&sb[ct*4+j], s); atomicAdd(&qb[ct*4+j], q);
  }
  __syncthreads();
  if(tid<64){
    float* ps = pstats + (size_t)(blockIdx.x & (NREP-1))*512;
    atomicAdd(&ps[128+tid], sb[tid]); atomicAdd(&ps[192+tid], qb[tid]);
  }
}

__global__ __launch_bounds__(256) void k_stats2(const float* __restrict__ xyz,
                                                const float* __restrict__ feat,
                                                const float* __restrict__ cxyz,
                                                const int* __restrict__ gidx,
                                                const float* __restrict__ W1,
                                                const float* __restrict__ coef,
                                                const float* __restrict__ W2,
                                                float* __restrict__ pstats){
  stats2_body<false>(xyz,feat,cxyz,gidx,W1,coef,W2,pstats,nullptr);
}
__global__ __launch_bounds__(256) void k_stats2m(const float* __restrict__ xyz,
                                                 const float* __restrict__ feat,
                                                 const float* __restrict__ cxyz,
                                                 const int* __restrict__ gidx,
                                                 const float* __restrict__ W1,
                                                 const float* __restrict__ coef,
                                                 const float* __restrict__ W2,
                                                 float* __restrict__ pstats,
                                                 float* __restrict__ Z2){
  stats2_body<true>(xyz,feat,cxyz,gidx,W1,coef,W2,pstats,Z2);
}

// ------------------------------------------- layer-3 (fallback: full recompute)
__global__ __launch_bounds__(256) void k_layer3(const float* __restrict__ xyz,
                                                const float* __restrict__ feat,
                                                const float* __restrict__ cxyz,
                                                const int* __restrict__ gidx,
                                                const float* __restrict__ W1,
                                                const float* __restrict__ coef,
                                                const float* __restrict__ W2,
                                                const float* __restrict__ W3,
                                                float* __restrict__ pstats,
                                                float* __restrict__ premax){
  __shared__ __align__(16) float INt[9*68];
  __shared__ __align__(16) float A1t[64*68];
  __shared__ float af1A[64], af1B[64], af2A[64], af2B[64];
  __shared__ unsigned mx[256];
  __shared__ float s3b[256], q3b[256];
  const int tid=threadIdx.x;
  if(tid<64){
    af1A[tid]=coef[tid];     af1B[tid]=coef[64+tid];
    af2A[tid]=coef[128+tid]; af2B[tid]=coef[192+tid];
  }
  mx[tid]=0u; s3b[tid]=0.f; q3b[tid]=0.f;
  stage_in(INt, blockIdx.x*64, xyz, feat, cxyz, gidx);
  __syncthreads();
  const int rt=tid&15, ct=tid>>4;
  float acc1[4][4];
  gemm1(INt, W1, rt, ct, acc1);
#pragma unroll
  for(int j=0;j<4;j++){
    const int o=ct*4+j; const float A=af1A[o], Bc=af1B[o];
#pragma unroll
    for(int i=0;i<4;i++) A1t[o*68 + rt*4+i] = fmaxf(acc1[i][j]*A+Bc, 0.f);
  }
  __syncthreads();
  float acc2[4][4];
#pragma unroll
  for(int i=0;i<4;i++)
#pragma unroll
    for(int j=0;j<4;j++) acc2[i][j]=0.f;
#pragma unroll
  for(int c=0;c<64;c++){
    const float4 a = *(const float4*)&A1t[c*68 + rt*4];
    const float4 w = *(const float4*)&W2[c*64 + ct*4];
    const float av[4]={a.x,a.y,a.z,a.w}, wv[4]={w.x,w.y,w.z,w.w};
#pragma unroll
    for(int i=0;i<4;i++)
#pragma unroll
      for(int j=0;j<4;j++) acc2[i][j] += av[i]*wv[j];
  }
  float a2v[4][4];
#pragma unroll
  for(int j=0;j<4;j++){
    const int o=ct*4+j; const float A=af2A[o], Bc=af2B[o];
#pragma unroll
    for(int i=0;i<4;i++) a2v[i][j]=fmaxf(acc2[i][j]*A+Bc, 0.f);
  }
  __syncthreads();
#pragma unroll
  for(int j=0;j<4;j++)
#pragma unroll
    for(int i=0;i<4;i++) A1t[(ct*4+j)*68 + rt*4+i] = a2v[i][j];
  __syncthreads();
  float acc3[4][8];
#pragma unroll
  for(int i=0;i<4;i++)
#pragma unroll
    for(int j=0;j<8;j++) acc3[i][j]=0.f;
#pragma unroll
  for(int c=0;c<64;c++){
    const float4 a  = *(const float4*)&A1t[c*68 + rt*4];
    const float4 w0 = *(const float4*)&W3[c*128 + ct*8];
    const float4 w1 = *(const float4*)&W3[c*128 + ct*8 + 4];
    const float av[4]={a.x,a.y,a.z,a.w};
    const float wv[8]={w0.x,w0.y,w0.z,w0.w,w1.x,w1.y,w1.z,w1.w};
#pragma unroll
    for(int i=0;i<4;i++)
#pragma unroll
      for(int j=0;j<8;j++) acc3[i][j] += av[i]*wv[j];
  }
  const int g = rt>>3;
#pragma unroll
  for(int j=0;j<8;j++){
    const int o=ct*8+j;
    float lm=acc3[0][j], s=0.f, q=0.f;
#pragma unroll
    for(int i=0;i<4;i++){ float v=acc3[i][j]; lm=fmaxf(lm,v); s+=v; q+=v*v; }
    atomicMax(&mx[g*128+o], fkey(lm));
    atomicAdd(&s3b[g*128+o], s);
    atomicAdd(&q3b[g*128+o], q);
  }
  __syncthreads();
  {
    const int gg=tid>>7, o=tid&127;
    const int cid = blockIdx.x*2+gg;
    premax[(size_t)cid*128+o] = funkey(mx[tid]);
  }
  if(tid<128){
    float* ps = pstats + (size_t)(blockIdx.x & (NREP-1))*512;
    atomicAdd(&ps[256+tid], s3b[tid]+s3b[128+tid]);
    atomicAdd(&ps[384+tid], q3b[tid]+q3b[128+tid]);
  }
}

// ------------------------------------------- layer-3 LEAN: reads materialized Z2
// R22: W3 (32 KB) staged into LDS. Mechanism: gemm3 issues 128 global float4
// W3 reads per thread; Z2's 134 MB stream evicts L1 (32 KB) so W3 runs at L2
// latency. LDS copy (issued before barrier 1, latency hidden under Z2 load)
// converts them to ds_read_b128 and drops 64-bit W3 address math. LDS 20K→52K:
// LDS-limit 3 blocks/CU, VGPR limit (~acc3+frags) binds first → free.
__global__ __launch_bounds__(256) void k_layer3z(const float* __restrict__ Z2,
                                                 const float* __restrict__ coef,
                                                 const float* __restrict__ W3,
                                                 float* __restrict__ pstats,
                                                 float* __restrict__ premax){
  __shared__ __align__(16) float A2t[64*68];
  __shared__ __align__(16) float W3l[64*128];
  __shared__ float af2A[64], af2B[64];
  __shared__ unsigned mx[256];
  __shared__ float s3b[256], q3b[256];
  const int tid=threadIdx.x;
  if(tid<64){
    af2A[tid]=coef[128+tid]; af2B[tid]=coef[192+tid];
  }
  mx[tid]=0u; s3b[tid]=0.f; q3b[tid]=0.f;
  // stage W3 → LDS (coalesced 8×float4/thread); visibility guaranteed by
  // the second __syncthreads() before gemm3 reads it.
#pragma unroll
  for(int i=0;i<8;i++){
    ((float4*)W3l)[tid + i*256] = ((const float4*)W3)[tid + i*256];
  }
  __syncthreads();
  {
    const int row = tid>>2, cq = (tid&3)*16;
    const float* zr = Z2 + ((size_t)blockIdx.x*64 + row)*64 + cq;
    const float4 z0 = *(const float4*)(zr);
    const float4 z1 = *(const float4*)(zr+4);
    const float4 z2 = *(const float4*)(zr+8);
    const float4 z3 = *(const float4*)(zr+12);
    const float zz[16]={z0.x,z0.y,z0.z,z0.w, z1.x,z1.y,z1.z,z1.w,
                        z2.x,z2.y,z2.z,z2.w, z3.x,z3.y,z3.z,z3.w};
#pragma unroll
    for(int u=0;u<16;u++){
      const int c = cq+u;
      A2t[c*68+row] = fmaxf(zz[u]*af2A[c]+af2B[c], 0.f);
    }
  }
  __syncthreads();
  const int rt=tid&15, ct=tid>>4;
  float acc3[4][8];
#pragma unroll
  for(int i=0;i<4;i++)
#pragma unroll
    for(int j=0;j<8;j++) acc3[i][j]=0.f;
#pragma unroll
  for(int c=0;c<64;c++){
    const float4 a  = *(const float4*)&A2t[c*68 + rt*4];
    const float4 w0 = *(const float4*)&W3l[c*128 + ct*8];
    const float4 w1 = *(const float4*)&W3l[c*128 + ct*8 + 4];
    const float av[4]={a.x,a.y,a.z,a.w};
    const float wv[8]={w0.x,w0.y,w0.z,w0.w,w1.x,w1.y,w1.z,w1.w};
#pragma unroll
    for(int i=0;i<4;i++)
#pragma unroll
      for(int j=0;j<8;j++) acc3[i][j] += av[i]*wv[j];
  }
  const int g = rt>>3;
#pragma unroll
  for(int j=0;j<8;j++){
    const int o=ct*8+j;
    float lm=acc3[0][j], s=0.f, q=0.f;
#pragma unroll
    for(int i=0;i<4;i++){ float v=acc3[i][j]; lm=fmaxf(lm,v); s+=v; q+=v*v; }
    atomicMax(&mx[g*128+o], fkey(lm));
    atomicAdd(&s3b[g*128+o], s);
    atomicAdd(&q3b[g*128+o], q);
  }
  __syncthreads();
  {
    const int gg=tid>>7, o=tid&127;
    const int cid = blockIdx.x*2+gg;
    premax[(size_t)cid*128+o] = funkey(mx[tid]);
  }
  if(tid<128){
    float* ps = pstats + (size_t)(blockIdx.x & (NREP-1))*512;
    atomicAdd(&ps[256+tid], s3b[tid]+s3b[128+tid]);
    atomicAdd(&ps[384+tid], q3b[tid]+q3b[128+tid]);
  }
}

// ------------------------------------------- fold layer-3 partials -> cstats
__global__ __launch_bounds__(256) void k_red3(const float* __restrict__ pstats,
                                              float* __restrict__ cstats){
  const int t = threadIdx.x;   // 256: [0..127]=sums, [128..255]=sumsq
  cstats[t] = fold_rep(pstats, 256+t);
}

// ------------------------------------------- final BN+relu (in place on outf)
__global__ __launch_bounds__(256) void k_final(const float* __restrict__ cstats,
                                               const float* __restrict__ g3,
                                               const float* __restrict__ b3,
                                               float* __restrict__ outf){
  const int i = blockIdx.x*256 + threadIdx.x;
  const int o = i & 127;
  float m  = cstats[o]/RNF;
  float vv = cstats[128+o]/RNF - m*m;
  float A  = rsqrtf(vv+EPSV)*g3[o];
  float Bc = b3[o]-m*A;
  float v  = outf[i];
  outf[i] = fmaxf(v*A+Bc, 0.f);
}

extern "C" void kernel_launch(void* const* d_in, const int* in_sizes, int n_in,
                              void* d_out, int out_size, void* d_ws, size_t ws_size,
                              hipStream_t stream){
  const float* xyz  = (const float*)d_in[0];
  const float* feat = (const float*)d_in[1];
  const float* W1   = (const float*)d_in[2];
  const float* g1   = (const float*)d_in[3];
  const float* b1   = (const float*)d_in[4];
  const float* W2   = (const float*)d_in[5];
  const float* g2   = (const float*)d_in[6];
  const float* b2   = (const float*)d_in[7];
  const float* W3   = (const float*)d_in[8];
  const float* g3   = (const float*)d_in[9];
  const float* b3   = (const float*)d_in[10];
  float* out  = (float*)d_out;
  float* cxyz = out;                     // (16,1024,3)
  float* outf = out + 16*1024*3;         // (16,1024,128) — premax staging then final
  // ws layout: [pstats 64x512 f32 @0 (128KB)][cstats 256 f32 @131072]
  //            [coef 256 f32 @132096: A1,B1,A2,B2][gidx 2MB @133120]
  //            [Z2 134MB @2230272 (fast path)]
  float* pstats = (float*)d_ws;
  float* cstats = (float*)((char*)d_ws + 131072);
  float* coef   = (float*)((char*)d_ws + 132096);
  int*   gidx   = (int*)((char*)d_ws + 133120);
  float* Z2     = (float*)((char*)d_ws + 133120 + (size_t)RTOT*4);
  const size_t need = 133120 + (size_t)RTOT*4 + (size_t)RTOT*64*4;  // ≈136.4 MB
  const bool fast = (ws_size >= need);   // ws_size constant per harness → same path every call

  hipMemsetAsync(pstats, 0, (size_t)NREP*512*sizeof(float), stream);
  k_fps   <<<16,   256,  0, stream>>>(xyz, cxyz);
  k_select<<<4096, 256,  0, stream>>>(xyz, cxyz, gidx);
  k_stats1<<<8192, 256,  0, stream>>>(xyz, feat, cxyz, gidx, W1, pstats);
  k_coef  <<<1,    64,   0, stream>>>(pstats, g1, b1, coef, 0);        // A1,B1
  if(fast){
    k_stats2m<<<8192, 256, 0, stream>>>(xyz, feat, cxyz, gidx, W1, coef, W2, pstats, Z2);
    k_coef  <<<1,    64,  0, stream>>>(pstats, g2, b2, coef+128, 128); // A2,B2
    k_layer3z<<<8192, 256, 0, stream>>>(Z2, coef, W3, pstats, outf);
  }else{
    k_stats2 <<<8192, 256, 0, stream>>>(xyz, feat, cxyz, gidx, W1, coef, W2, pstats);
    k_coef  <<<1,    64,  0, stream>>>(pstats, g2, b2, coef+128, 128); // A2,B2
    k_layer3 <<<8192, 256, 0, stream>>>(xyz, feat, cxyz, gidx, W1, coef, W2, W3, pstats, outf);
  }
  k_red3  <<<1,    256,  0, stream>>>(pstats, cstats);
  k_final <<<8192, 256,  0, stream>>>(cstats, g3, b3, outf);
}

// Round 8
// 1389.019 us; speedup vs baseline: 1.1232x; 1.0614x over previous
//
#include <hip/hip_runtime.h>

#define BN_   16
#define NPTS  4096
#define DFEAT 6
#define SCTR  1024
#define KNN   32
#define RTOT  (BN_*SCTR*KNN)   /* 524288 rows */
#define EPSV  1e-5f
#define RNF   524288.0f
#define NREP  64               /* replicated stats copies */

__device__ __forceinline__ float fmulx(float a, float b){ return __fmul_rn(a,b); }
__device__ __forceinline__ float faddx(float a, float b){ return __fadd_rn(a,b); }
__device__ __forceinline__ float fsubx(float a, float b){ return __fsub_rn(a,b); }
// naive (non-FMA) sum of squares — LOCKED by R5/R6 pass.
__device__ __forceinline__ float sq3x(float x, float y, float z){
  return faddx(faddx(fmulx(x,x), fmulx(y,y)), fmulx(z,z));
}
// FMA-contracted inner product (matches np einsum) — LOCKED by R5 pass.
__device__ __forceinline__ float dot3fma(float ax, float ay, float az,
                                         float bx, float by, float bz){
  return __fmaf_rn(az, bz, __fmaf_rn(ay, by, __fmul_rn(ax, bx)));
}

__device__ __forceinline__ unsigned fkey(float f){
  unsigned u = __float_as_uint(f);
  return (u & 0x80000000u) ? ~u : (u | 0x80000000u);
}
__device__ __forceinline__ float funkey(unsigned k){
  return (k & 0x80000000u) ? __uint_as_float(k & 0x7fffffffu) : __uint_as_float(~k);
}

// ---------------- DPP wave64 reductions (VALU-only; proven on HW in R12).
// R17 POST-MORTEM: DPP row-sum chains in wide-unrolled stats EPILOGUES spill
// (VGPR=256, 9.7 GB scratch HBM). DPP stays ONLY in argmax reductions.
// R19 POST-MORTEM: merged u64 (value,~j) DPP chain is NOT cheaper than two
// u32 chains — REGRESSED +37 µs. k_fps is FROZEN at the R12/R14 form.
// R20 POST-MORTEM: octant-cached select with qv[8]/qt[8] arrays + 8-way
// switch REGRESSED ~90 µs vs quarter-cache with NAMED SCALARS (q0v..q3v) —
// array-in-branchy-joins demotes to scratch. k_select FROZEN at quarter form.
// R22 POST-MORTEM: W3→LDS staging in k_layer3z = NEUTRAL (±4 µs) — layer3z
// inner loop is not W3-latency-bound. Kept (harmless).
template<int CTRL>
__device__ __forceinline__ unsigned dpp_mv(unsigned v){
  return (unsigned)__builtin_amdgcn_update_dpp((int)v, (int)v, CTRL, 0xf, 0xf, false);
}
__device__ __forceinline__ unsigned wave_umax_b(unsigned v){
  unsigned o;
  o=dpp_mv<0x111>(v); v=v>o?v:o;   // row_shr:1
  o=dpp_mv<0x112>(v); v=v>o?v:o;   // row_shr:2
  o=dpp_mv<0x114>(v); v=v>o?v:o;   // row_shr:4
  o=dpp_mv<0x118>(v); v=v>o?v:o;   // row_shr:8
  o=dpp_mv<0x142>(v); v=v>o?v:o;   // row_bcast:15
  o=dpp_mv<0x143>(v); v=v>o?v:o;   // row_bcast:31
  return (unsigned)__builtin_amdgcn_readlane((int)v, 63);
}
__device__ __forceinline__ unsigned wave_umin_b(unsigned v){
  unsigned o;
  o=dpp_mv<0x111>(v); v=v<o?v:o;
  o=dpp_mv<0x112>(v); v=v<o?v:o;
  o=dpp_mv<0x114>(v); v=v<o?v:o;
  o=dpp_mv<0x118>(v); v=v<o?v:o;
  o=dpp_mv<0x142>(v); v=v<o?v:o;
  o=dpp_mv<0x143>(v); v=v<o?v:o;
  return (unsigned)__builtin_amdgcn_readlane((int)v, 63);
}

// ---------------------------------------------------------------- FPS
// R12/R14 FROZEN version (620-627 µs, measured 10×+): 4 waves, s_barrier per
// iter, two-phase u32 DPP argmax, winner coords via uniform broadcast LDS read.
// Failed variants (do not redo): 8-wave (R16, +64), LDS spin-poll (R15, +156),
// merged u64 chain + coord-carry slots (R19, +37).
__global__ __launch_bounds__(256) void k_fps(const float* __restrict__ xyz,
                                             float* __restrict__ cxyz){
  const int b = blockIdx.x, tid = threadIdx.x;
  const int wave = tid>>6, lane = tid&63;
  const float* X = xyz + (size_t)b*NPTS*3;
  __shared__ float Xl[NPTS*3];
  __shared__ float Cl[SCTR*3];
  __shared__ unsigned long long slot[2][4];
  for(int i=tid;i<NPTS*3;i+=256) Xl[i]=X[i];
  __syncthreads();
  float px[16],py[16],pz[16],mind[16];
  const float c0x=Xl[0], c0y=Xl[1], c0z=Xl[2];
#pragma unroll
  for(int t=0;t<16;t++){
    const int j = lane + 64*(wave*16+t);
    px[t]=Xl[j*3]; py[t]=Xl[j*3+1]; pz[t]=Xl[j*3+2];
    mind[t]=sq3x(fsubx(px[t],c0x), fsubx(py[t],c0y), fsubx(pz[t],c0z));
  }
  if(tid==0){ Cl[0]=c0x; Cl[1]=c0y; Cl[2]=c0z; }
  float bv=-1.0f; int bj=0x7fffffff;
#pragma unroll
  for(int t=0;t<16;t++){
    const int j = lane + 64*(wave*16+t);
    if(mind[t]>bv){ bv=mind[t]; bj=j; }
  }
  for(int it=1; it<SCTR; ++it){
    const unsigned uv = __float_as_uint(bv);
    const unsigned M  = wave_umax_b(uv);
    const unsigned nj = (uv == M) ? ~(unsigned)bj : 0u;
    const unsigned NJ = wave_umax_b(nj);
    if(lane==0) slot[it&1][wave] = ((unsigned long long)M<<32) | NJ;
    __syncthreads();          // parity double-buffer prevents WAR
    unsigned long long k0=slot[it&1][0], k1=slot[it&1][1],
                       k2=slot[it&1][2], k3=slot[it&1][3];
    unsigned long long ka = k0>k1?k0:k1;
    unsigned long long kb = k2>k3?k2:k3;
    unsigned long long kw = ka>kb?ka:kb;
    const int w = (int)(~(unsigned)kw);          // j < 4096
    const float cx=Xl[w*3], cy=Xl[w*3+1], cz=Xl[w*3+2];
    if(tid==0){ Cl[it*3]=cx; Cl[it*3+1]=cy; Cl[it*3+2]=cz; }
    bv=-1.0f; bj=0x7fffffff;
#pragma unroll
    for(int t=0;t<16;t++){
      float d = sq3x(fsubx(px[t],cx), fsubx(py[t],cy), fsubx(pz[t],cz));
      float nm = fminf(mind[t], d);
      mind[t]=nm;
      const int j = lane + 64*(wave*16+t);
      if(nm>bv){ bv=nm; bj=j; }
    }
  }
  __syncthreads();
  float* O = cxyz + (size_t)b*SCTR*3;
  for(int i=tid;i<SCTR*3;i+=256) O[i]=Cl[i];
}

// ------------------------------------------- 32-NN select
// R16/R18 FROZEN quarter-cached version. NAMED SCALAR candidates q0v..q3v —
// do NOT convert to arrays (R20: +90 µs scratch-demotion regression).
__global__ __launch_bounds__(256) void k_select(const float* __restrict__ xyz,
                                                const float* __restrict__ cxyz,
                                                int* __restrict__ gidx){
  const int lane = threadIdx.x & 63;
  const int cid  = blockIdx.x*4 + (threadIdx.x>>6);
  const int b = cid>>10;
  const float* X = xyz + (size_t)b*NPTS*3;
  const float* C = cxyz + (size_t)cid*3;
  const float cx=C[0], cy=C[1], cz=C[2];
  const float a2 = sq3x(cx,cy,cz);
  float d[64];
#pragma unroll
  for(int t=0;t<64;t++){
    int j = lane + (t<<6);
    float x=X[j*3], y=X[j*3+1], z=X[j*3+2];
    float b2 = sq3x(x,y,z);
    float dt = dot3fma(cx,cy,cz, x,y,z);
    float dd = fsubx(faddx(a2,b2), fmulx(2.0f,dt));
    d[t] = fmaxf(dd, 0.0f);
  }
  float q0v=3.0e38f, q1v=3.0e38f, q2v=3.0e38f, q3v=3.0e38f;
  int   q0t=0, q1t=16, q2t=32, q3t=48;
#pragma unroll
  for(int k=0;k<16;k++){ if(d[k]    < q0v){ q0v=d[k];    q0t=k;    } }
#pragma unroll
  for(int k=0;k<16;k++){ if(d[16+k] < q1v){ q1v=d[16+k]; q1t=16+k; } }
#pragma unroll
  for(int k=0;k<16;k++){ if(d[32+k] < q2v){ q2v=d[32+k]; q2t=32+k; } }
#pragma unroll
  for(int k=0;k<16;k++){ if(d[48+k] < q3v){ q3v=d[48+k]; q3t=48+k; } }
  unsigned long long taken = 0ull;
  int* out = gidx + (size_t)cid*KNN;
#pragma unroll 1
  for(int r=0;r<KNN;r++){
    float mv = q0v; int mt = q0t;
    if(q1v < mv){ mv=q1v; mt=q1t; }
    if(q2v < mv){ mv=q2v; mt=q2t; }
    if(q3v < mv){ mv=q3v; mt=q3t; }
    const unsigned um = __float_as_uint(mv);   // d >= 0 → bit order = value order
    const unsigned Mw = wave_umin_b(um);
    const unsigned jc = (um == Mw) ? (unsigned)(lane + (mt<<6)) : 0xffffffffu;
    const unsigned WJ = wave_umin_b(jc);
    const int wl = (int)(WJ & 63u);
    const int wt = (int)(WJ >> 6);
    if(lane == wl){
      out[r] = (int)WJ;
      taken |= (1ull << wt);
    }
    const int wq = wt >> 4;
#define RESCAN_Q(QV,QT,BASE) \
    if(lane == wl){ \
      float nv=3.0e38f; int nt=BASE; \
      _Pragma("unroll") \
      for(int k2=0;k2<16;k2++){ \
        if(!(taken & (1ull<<(BASE+k2))) && d[BASE+k2] < nv){ nv=d[BASE+k2]; nt=BASE+k2; } \
      } \
      QV=nv; QT=nt; \
    }
    if(wq==0)      { RESCAN_Q(q0v,q0t,0)  }
    else if(wq==1) { RESCAN_Q(q1v,q1t,16) }
    else if(wq==2) { RESCAN_Q(q2v,q2t,32) }
    else           { RESCAN_Q(q3v,q3t,48) }
#undef RESCAN_Q
  }
}

// ------------------------------------------------- shared tile helpers
__device__ __forceinline__ void stage_in(float* INt, int rbase,
                                         const float* __restrict__ xyz,
                                         const float* __restrict__ feat,
                                         const float* __restrict__ cxyz,
                                         const int* __restrict__ gidx){
  const int tid = threadIdx.x;
  const int row = tid>>2, sub = tid&3;
  const int r  = rbase + row;
  const int bb = r>>15, ss=(r>>5)&1023;
  const int idx = gidx[r];
  if(sub==0){
    const float* P = xyz  + ((size_t)bb*NPTS + idx)*3;
    const float* C = cxyz + ((size_t)(bb*SCTR)+ss)*3;
    INt[0*68+row] = P[0]-C[0];
    INt[1*68+row] = P[1]-C[1];
    INt[2*68+row] = P[2]-C[2];
  }else{
    const float* F = feat + ((size_t)bb*NPTS + idx)*6;
    const int c = (sub-1)*2;
    INt[(3+c)*68+row] = F[c];
    INt[(4+c)*68+row] = F[c+1];
  }
}

__device__ __forceinline__ void gemm1(const float* INt, const float* __restrict__ W1,
                                      int rt, int ct, float acc[4][4]){
#pragma unroll
  for(int i=0;i<4;i++)
#pragma unroll
    for(int j=0;j<4;j++) acc[i][j]=0.f;
#pragma unroll
  for(int c=0;c<9;c++){
    const float4 a = *(const float4*)&INt[c*68 + rt*4];
    const float4 w = *(const float4*)&W1[c*64 + ct*4];
    const float av[4]={a.x,a.y,a.z,a.w}, wv[4]={w.x,w.y,w.z,w.w};
#pragma unroll
    for(int i=0;i<4;i++)
#pragma unroll
      for(int j=0;j<4;j++) acc[i][j] += av[i]*wv[j];
  }
}

// fold one channel across the NREP replicated copies
__device__ __forceinline__ float fold_rep(const float* __restrict__ pstats, int off){
  float s=0.f;
#pragma unroll 8
  for(int c=0;c<NREP;c++) s += pstats[c*512 + off];
  return s;
}

// -------------------------------------- BN affine coef precompute (R17, ~−21µs)
__global__ __launch_bounds__(64) void k_coef(const float* __restrict__ pstats,
                                             const float* __restrict__ g,
                                             const float* __restrict__ b,
                                             float* __restrict__ coefo,
                                             int off){
  const int t = threadIdx.x;   // 64
  float sm = fold_rep(pstats, off+t);
  float sq = fold_rep(pstats, off+64+t);
  float m  = sm/RNF;
  float vv = sq/RNF - m*m;
  float A  = rsqrtf(vv+EPSV)*g[t];
  coefo[t]    = A;
  coefo[64+t] = b[t]-m*A;
}

// ---------------------------------------------------------------- layer-1 stats
// R23: 4 row-tiles per block (grid 2048). Inner loops byte-identical; per-j
// stats accumulate in NAMED registers (s0..s3/q0..q3 — static idx, rule #20)
// across tiles; epilogue (LDS atomics + global atomics) runs ONCE per block:
// 4× fewer epilogue atomics / zero-inits / launches.
__global__ __launch_bounds__(256) void k_stats1(const float* __restrict__ xyz,
                                                const float* __restrict__ feat,
                                                const float* __restrict__ cxyz,
                                                const int* __restrict__ gidx,
                                                const float* __restrict__ W1,
                                                float* __restrict__ pstats){
  __shared__ __align__(16) float INt[9*68];
  __shared__ float sb[64], qb[64];
  const int tid=threadIdx.x;
  if(tid<64){ sb[tid]=0.f; qb[tid]=0.f; }
  const int rt=tid&15, ct=tid>>4;
  float s0=0.f,s1=0.f,s2=0.f,s3=0.f, p0=0.f,p1=0.f,p2=0.f,p3=0.f;
#pragma unroll 1
  for(int h=0;h<4;h++){
    if(h) __syncthreads();                       // WAR on INt
    stage_in(INt, blockIdx.x*256 + h*64, xyz, feat, cxyz, gidx);
    __syncthreads();
    float acc[4][4];
    gemm1(INt, W1, rt, ct, acc);
    {
      float s=0.f,q=0.f;
#pragma unroll
      for(int i=0;i<4;i++){ float v=acc[i][0]; s+=v; q+=v*v; }
      s0+=s; p0+=q;
    }
    {
      float s=0.f,q=0.f;
#pragma unroll
      for(int i=0;i<4;i++){ float v=acc[i][1]; s+=v; q+=v*v; }
      s1+=s; p1+=q;
    }
    {
      float s=0.f,q=0.f;
#pragma unroll
      for(int i=0;i<4;i++){ float v=acc[i][2]; s+=v; q+=v*v; }
      s2+=s; p2+=q;
    }
    {
      float s=0.f,q=0.f;
#pragma unroll
      for(int i=0;i<4;i++){ float v=acc[i][3]; s+=v; q+=v*v; }
      s3+=s; p3+=q;
    }
  }
  atomicAdd(&sb[ct*4+0], s0); atomicAdd(&qb[ct*4+0], p0);
  atomicAdd(&sb[ct*4+1], s1); atomicAdd(&qb[ct*4+1], p1);
  atomicAdd(&sb[ct*4+2], s2); atomicAdd(&qb[ct*4+2], p2);
  atomicAdd(&sb[ct*4+3], s3); atomicAdd(&qb[ct*4+3], p3);
  __syncthreads();
  if(tid<64){
    float* ps = pstats + (size_t)(blockIdx.x & (NREP-1))*512;
    atomicAdd(&ps[tid], sb[tid]); atomicAdd(&ps[64+tid], qb[tid]);
  }
}

// -------------------------------------- layer-2 stats core (optionally writes Z2)
// R23: 4 row-tiles per block (grid 2048), same amortization as k_stats1.
// Z2 row base uses the GLOBAL tile index → Z2 contents bit-identical.
template<bool WRITEZ>
__device__ __forceinline__ void stats2_body(const float* xyz, const float* feat,
                                            const float* cxyz, const int* gidx,
                                            const float* W1,
                                            const float* __restrict__ coef,
                                            const float* __restrict__ W2,
                                            float* pstats, float* Z2){
  __shared__ __align__(16) float INt[9*68];
  __shared__ __align__(16) float A1t[64*68];
  __shared__ float af1A[64], af1B[64];
  __shared__ float sb[64], qb[64];
  const int tid=threadIdx.x;
  if(tid<64){
    af1A[tid]=coef[tid]; af1B[tid]=coef[64+tid];
    sb[tid]=0.f; qb[tid]=0.f;
  }
  const int rt=tid&15, ct=tid>>4;
  float s0=0.f,s1=0.f,s2=0.f,s3=0.f, p0=0.f,p1=0.f,p2=0.f,p3=0.f;
#pragma unroll 1
  for(int h=0;h<4;h++){
    if(h) __syncthreads();                       // WAR on INt/A1t
    stage_in(INt, blockIdx.x*256 + h*64, xyz, feat, cxyz, gidx);
    __syncthreads();
    float acc1[4][4];
    gemm1(INt, W1, rt, ct, acc1);
#pragma unroll
    for(int j=0;j<4;j++){
      const int o=ct*4+j; const float A=af1A[o], Bc=af1B[o];
#pragma unroll
      for(int i=0;i<4;i++) A1t[o*68 + rt*4+i] = fmaxf(acc1[i][j]*A+Bc, 0.f);
    }
    __syncthreads();
    float acc2[4][4];
#pragma unroll
    for(int i=0;i<4;i++)
#pragma unroll
      for(int j=0;j<4;j++) acc2[i][j]=0.f;
#pragma unroll
    for(int c=0;c<64;c++){
      const float4 a = *(const float4*)&A1t[c*68 + rt*4];
      const float4 w = *(const float4*)&W2[c*64 + ct*4];
      const float av[4]={a.x,a.y,a.z,a.w}, wv[4]={w.x,w.y,w.z,w.w};
#pragma unroll
      for(int i=0;i<4;i++)
#pragma unroll
        for(int j=0;j<4;j++) acc2[i][j] += av[i]*wv[j];
    }
    if(WRITEZ){
#pragma unroll
      for(int i=0;i<4;i++){
        float4 v = make_float4(acc2[i][0],acc2[i][1],acc2[i][2],acc2[i][3]);
        *(float4*)&Z2[((size_t)(blockIdx.x*4+h)*64 + rt*4+i)*64 + ct*4] = v;
      }
    }
    {
      float s=0.f,q=0.f;
#pragma unroll
      for(int i=0;i<4;i++){ float v=acc2[i][0]; s+=v; q+=v*v; }
      s0+=s; p0+=q;
    }
    {
      float s=0.f,q=0.f;
#pragma unroll
      for(int i=0;i<4;i++){ float v=acc2[i][1]; s+=v; q+=v*v; }
      s1+=s; p1+=q;
    }
    {
      float s=0.f,q=0.f;
#pragma unroll
      for(int i=0;i<4;i++){ float v=acc2[i][2]; s+=v; q+=v*v; }
      s2+=s; p2+=q;
    }
    {
      float s=0.f,q=0.f;
#pragma unroll
      for(int i=0;i<4;i++){ float v=acc2[i][3]; s+=v; q+=v*v; }
      s3+=s; p3+=q;
    }
  }
  atomicAdd(&sb[ct*4+0], s0); atomicAdd(&qb[ct*4+0], p0);
  atomicAdd(&sb[ct*4+1], s1); atomicAdd(&qb[ct*4+1], p1);
  atomicAdd(&sb[ct*4+2], s2); atomicAdd(&qb[ct*4+2], p2);
  atomicAdd(&sb[ct*4+3], s3); atomicAdd(&qb[ct*4+3], p3);
  __syncthreads();
  if(tid<64){
    float* ps = pstats + (size_t)(blockIdx.x & (NREP-1))*512;
    atomicAdd(&ps[128+tid], sb[tid]); atomicAdd(&ps[192+tid], qb[tid]);
  }
}

__global__ __launch_bounds__(256) void k_stats2(const float* __restrict__ xyz,
                                                const float* __restrict__ feat,
                                                const float* __restrict__ cxyz,
                                                const int* __restrict__ gidx,
                                                const float* __restrict__ W1,
                                                const float* __restrict__ coef,
                                                const float* __restrict__ W2,
                                                float* __restrict__ pstats){
  stats2_body<false>(xyz,feat,cxyz,gidx,W1,coef,W2,pstats,nullptr);
}
__global__ __launch_bounds__(256) void k_stats2m(const float* __restrict__ xyz,
                                                 const float* __restrict__ feat,
                                                 const float* __restrict__ cxyz,
                                                 const int* __restrict__ gidx,
                                                 const float* __restrict__ W1,
                                                 const float* __restrict__ coef,
                                                 const float* __restrict__ W2,
                                                 float* __restrict__ pstats,
                                                 float* __restrict__ Z2){
  stats2_body<true>(xyz,feat,cxyz,gidx,W1,coef,W2,pstats,Z2);
}

// ------------------------------------------- layer-3 (fallback: full recompute)
// Unchanged (slow path only). Grid stays 8192.
__global__ __launch_bounds__(256) void k_layer3(const float* __restrict__ xyz,
                                                const float* __restrict__ feat,
                                                const float* __restrict__ cxyz,
                                                const int* __restrict__ gidx,
                                                const float* __restrict__ W1,
                                                const float* __restrict__ coef,
                                                const float* __restrict__ W2,
                                                const float* __restrict__ W3,
                                                float* __restrict__ pstats,
                                                float* __restrict__ premax){
  __shared__ __align__(16) float INt[9*68];
  __shared__ __align__(16) float A1t[64*68];
  __shared__ float af1A[64], af1B[64], af2A[64], af2B[64];
  __shared__ unsigned mx[256];
  __shared__ float s3b[256], q3b[256];
  const int tid=threadIdx.x;
  if(tid<64){
    af1A[tid]=coef[tid];     af1B[tid]=coef[64+tid];
    af2A[tid]=coef[128+tid]; af2B[tid]=coef[192+tid];
  }
  mx[tid]=0u; s3b[tid]=0.f; q3b[tid]=0.f;
  stage_in(INt, blockIdx.x*64, xyz, feat, cxyz, gidx);
  __syncthreads();
  const int rt=tid&15, ct=tid>>4;
  float acc1[4][4];
  gemm1(INt, W1, rt, ct, acc1);
#pragma unroll
  for(int j=0;j<4;j++){
    const int o=ct*4+j; const float A=af1A[o], Bc=af1B[o];
#pragma unroll
    for(int i=0;i<4;i++) A1t[o*68 + rt*4+i] = fmaxf(acc1[i][j]*A+Bc, 0.f);
  }
  __syncthreads();
  float acc2[4][4];
#pragma unroll
  for(int i=0;i<4;i++)
#pragma unroll
    for(int j=0;j<4;j++) acc2[i][j]=0.f;
#pragma unroll
  for(int c=0;c<64;c++){
    const float4 a = *(const float4*)&A1t[c*68 + rt*4];
    const float4 w = *(const float4*)&W2[c*64 + ct*4];
    const float av[4]={a.x,a.y,a.z,a.w}, wv[4]={w.x,w.y,w.z,w.w};
#pragma unroll
    for(int i=0;i<4;i++)
#pragma unroll
      for(int j=0;j<4;j++) acc2[i][j] += av[i]*wv[j];
  }
  float a2v[4][4];
#pragma unroll
  for(int j=0;j<4;j++){
    const int o=ct*4+j; const float A=af2A[o], Bc=af2B[o];
#pragma unroll
    for(int i=0;i<4;i++) a2v[i][j]=fmaxf(acc2[i][j]*A+Bc, 0.f);
  }
  __syncthreads();
#pragma unroll
  for(int j=0;j<4;j++)
#pragma unroll
    for(int i=0;i<4;i++) A1t[(ct*4+j)*68 + rt*4+i] = a2v[i][j];
  __syncthreads();
  float acc3[4][8];
#pragma unroll
  for(int i=0;i<4;i++)
#pragma unroll
    for(int j=0;j<8;j++) acc3[i][j]=0.f;
#pragma unroll
  for(int c=0;c<64;c++){
    const float4 a  = *(const float4*)&A1t[c*68 + rt*4];
    const float4 w0 = *(const float4*)&W3[c*128 + ct*8];
    const float4 w1 = *(const float4*)&W3[c*128 + ct*8 + 4];
    const float av[4]={a.x,a.y,a.z,a.w};
    const float wv[8]={w0.x,w0.y,w0.z,w0.w,w1.x,w1.y,w1.z,w1.w};
#pragma unroll
    for(int i=0;i<4;i++)
#pragma unroll
      for(int j=0;j<8;j++) acc3[i][j] += av[i]*wv[j];
  }
  const int g = rt>>3;
#pragma unroll
  for(int j=0;j<8;j++){
    const int o=ct*8+j;
    float lm=acc3[0][j], s=0.f, q=0.f;
#pragma unroll
    for(int i=0;i<4;i++){ float v=acc3[i][j]; lm=fmaxf(lm,v); s+=v; q+=v*v; }
    atomicMax(&mx[g*128+o], fkey(lm));
    atomicAdd(&s3b[g*128+o], s);
    atomicAdd(&q3b[g*128+o], q);
  }
  __syncthreads();
  {
    const int gg=tid>>7, o=tid&127;
    const int cid = blockIdx.x*2+gg;
    premax[(size_t)cid*128+o] = funkey(mx[tid]);
  }
  if(tid<128){
    float* ps = pstats + (size_t)(blockIdx.x & (NREP-1))*512;
    atomicAdd(&ps[256+tid], s3b[tid]+s3b[128+tid]);
    atomicAdd(&ps[384+tid], q3b[tid]+q3b[128+tid]);
  }
}

// ------------------------------------------- layer-3 LEAN: reads materialized Z2
// R22 form (W3 in LDS, neutral-kept). Unchanged this round for isolation.
__global__ __launch_bounds__(256) void k_layer3z(const float* __restrict__ Z2,
                                                 const float* __restrict__ coef,
                                                 const float* __restrict__ W3,
                                                 float* __restrict__ pstats,
                                                 float* __restrict__ premax){
  __shared__ __align__(16) float A2t[64*68];
  __shared__ __align__(16) float W3l[64*128];
  __shared__ float af2A[64], af2B[64];
  __shared__ unsigned mx[256];
  __shared__ float s3b[256], q3b[256];
  const int tid=threadIdx.x;
  if(tid<64){
    af2A[tid]=coef[128+tid]; af2B[tid]=coef[192+tid];
  }
  mx[tid]=0u; s3b[tid]=0.f; q3b[tid]=0.f;
#pragma unroll
  for(int i=0;i<8;i++){
    ((float4*)W3l)[tid + i*256] = ((const float4*)W3)[tid + i*256];
  }
  __syncthreads();
  {
    const int row = tid>>2, cq = (tid&3)*16;
    const float* zr = Z2 + ((size_t)blockIdx.x*64 + row)*64 + cq;
    const float4 z0 = *(const float4*)(zr);
    const float4 z1 = *(const float4*)(zr+4);
    const float4 z2 = *(const float4*)(zr+8);
    const float4 z3 = *(const float4*)(zr+12);
    const float zz[16]={z0.x,z0.y,z0.z,z0.w, z1.x,z1.y,z1.z,z1.w,
                        z2.x,z2.y,z2.z,z2.w, z3.x,z3.y,z3.z,z3.w};
#pragma unroll
    for(int u=0;u<16;u++){
      const int c = cq+u;
      A2t[c*68+row] = fmaxf(zz[u]*af2A[c]+af2B[c], 0.f);
    }
  }
  __syncthreads();
  const int rt=tid&15, ct=tid>>4;
  float acc3[4][8];
#pragma unroll
  for(int i=0;i<4;i++)
#pragma unroll
    for(int j=0;j<8;j++) acc3[i][j]=0.f;
#pragma unroll
  for(int c=0;c<64;c++){
    const float4 a  = *(const float4*)&A2t[c*68 + rt*4];
    const float4 w0 = *(const float4*)&W3l[c*128 + ct*8];
    const float4 w1 = *(const float4*)&W3l[c*128 + ct*8 + 4];
    const float av[4]={a.x,a.y,a.z,a.w};
    const float wv[8]={w0.x,w0.y,w0.z,w0.w,w1.x,w1.y,w1.z,w1.w};
#pragma unroll
    for(int i=0;i<4;i++)
#pragma unroll
      for(int j=0;j<8;j++) acc3[i][j] += av[i]*wv[j];
  }
  const int g = rt>>3;
#pragma unroll
  for(int j=0;j<8;j++){
    const int o=ct*8+j;
    float lm=acc3[0][j], s=0.f, q=0.f;
#pragma unroll
    for(int i=0;i<4;i++){ float v=acc3[i][j]; lm=fmaxf(lm,v); s+=v; q+=v*v; }
    atomicMax(&mx[g*128+o], fkey(lm));
    atomicAdd(&s3b[g*128+o], s);
    atomicAdd(&q3b[g*128+o], q);
  }
  __syncthreads();
  {
    const int gg=tid>>7, o=tid&127;
    const int cid = blockIdx.x*2+gg;
    premax[(size_t)cid*128+o] = funkey(mx[tid]);
  }
  if(tid<128){
    float* ps = pstats + (size_t)(blockIdx.x & (NREP-1))*512;
    atomicAdd(&ps[256+tid], s3b[tid]+s3b[128+tid]);
    atomicAdd(&ps[384+tid], q3b[tid]+q3b[128+tid]);
  }
}

// ------------------------------------------- fold layer-3 partials -> cstats
__global__ __launch_bounds__(256) void k_red3(const float* __restrict__ pstats,
                                              float* __restrict__ cstats){
  const int t = threadIdx.x;   // 256: [0..127]=sums, [128..255]=sumsq
  cstats[t] = fold_rep(pstats, 256+t);
}

// ------------------------------------------- final BN+relu (in place on outf)
__global__ __launch_bounds__(256) void k_final(const float* __restrict__ cstats,
                                               const float* __restrict__ g3,
                                               const float* __restrict__ b3,
                                               float* __restrict__ outf){
  const int i = blockIdx.x*256 + threadIdx.x;
  const int o = i & 127;
  float m  = cstats[o]/RNF;
  float vv = cstats[128+o]/RNF - m*m;
  float A  = rsqrtf(vv+EPSV)*g3[o];
  float Bc = b3[o]-m*A;
  float v  = outf[i];
  outf[i] = fmaxf(v*A+Bc, 0.f);
}

extern "C" void kernel_launch(void* const* d_in, const int* in_sizes, int n_in,
                              void* d_out, int out_size, void* d_ws, size_t ws_size,
                              hipStream_t stream){
  const float* xyz  = (const float*)d_in[0];
  const float* feat = (const float*)d_in[1];
  const float* W1   = (const float*)d_in[2];
  const float* g1   = (const float*)d_in[3];
  const float* b1   = (const float*)d_in[4];
  const float* W2   = (const float*)d_in[5];
  const float* g2   = (const float*)d_in[6];
  const float* b2   = (const float*)d_in[7];
  const float* W3   = (const float*)d_in[8];
  const float* g3   = (const float*)d_in[9];
  const float* b3   = (const float*)d_in[10];
  float* out  = (float*)d_out;
  float* cxyz = out;                     // (16,1024,3)
  float* outf = out + 16*1024*3;         // (16,1024,128) — premax staging then final
  // ws layout: [pstats 64x512 f32 @0 (128KB)][cstats 256 f32 @131072]
  //            [coef 256 f32 @132096: A1,B1,A2,B2][gidx 2MB @133120]
  //            [Z2 134MB @2230272 (fast path)]
  float* pstats = (float*)d_ws;
  float* cstats = (float*)((char*)d_ws + 131072);
  float* coef   = (float*)((char*)d_ws + 132096);
  int*   gidx   = (int*)((char*)d_ws + 133120);
  float* Z2     = (float*)((char*)d_ws + 133120 + (size_t)RTOT*4);
  const size_t need = 133120 + (size_t)RTOT*4 + (size_t)RTOT*64*4;  // ≈136.4 MB
  const bool fast = (ws_size >= need);   // ws_size constant per harness → same path every call

  hipMemsetAsync(pstats, 0, (size_t)NREP*512*sizeof(float), stream);
  k_fps   <<<16,   256,  0, stream>>>(xyz, cxyz);
  k_select<<<4096, 256,  0, stream>>>(xyz, cxyz, gidx);
  k_stats1<<<2048, 256,  0, stream>>>(xyz, feat, cxyz, gidx, W1, pstats);
  k_coef  <<<1,    64,   0, stream>>>(pstats, g1, b1, coef, 0);        // A1,B1
  if(fast){
    k_stats2m<<<2048, 256, 0, stream>>>(xyz, feat, cxyz, gidx, W1, coef, W2, pstats, Z2);
    k_coef  <<<1,    64,  0, stream>>>(pstats, g2, b2, coef+128, 128); // A2,B2
    k_layer3z<<<8192, 256, 0, stream>>>(Z2, coef, W3, pstats, outf);
  }else{
    k_stats2 <<<2048, 256, 0, stream>>>(xyz, feat, cxyz, gidx, W1, coef, W2, pstats);
    k_coef  <<<1,    64,  0, stream>>>(pstats, g2, b2, coef+128, 128); // A2,B2
    k_layer3 <<<8192, 256, 0, stream>>>(xyz, feat, cxyz, gidx, W1, coef, W2, W3, pstats, outf);
  }
  k_red3  <<<1,    256,  0, stream>>>(pstats, cstats);
  k_final <<<8192, 256,  0, stream>>>(cstats, g3, b3, outf);
}